// Round 7
// baseline (378.344 us; speedup 1.0000x reference)
//
#include <hip/hip_runtime.h>
#include <math.h>

#define NN 100000
#define EE 1600000
#define FIN 128
#define DD 64
#define NG 64
#define NBINS ((NN + 255) / 256)   // 391 bins of 256 dst nodes
#define CH 8192                    // edges per pass1 block (= 256 threads * 32)

typedef unsigned int uint;
typedef unsigned short ushort;

// ---- ordered-float <-> uint mapping for atomicMax on floats ----
__device__ __forceinline__ unsigned f2ord(float f) {
  unsigned u = __float_as_uint(f);
  return (u & 0x80000000u) ? ~u : (u | 0x80000000u);
}
__device__ __forceinline__ float ord2f(unsigned m) {
  unsigned u = (m & 0x80000000u) ? (m & 0x7FFFFFFFu) : ~m;
  return __uint_as_float(u);
}
// ---- bf16 helpers (fp32 accumulate everywhere; RNE pack) ----
__device__ __forceinline__ float bflo(uint v) { return __uint_as_float(v << 16); }
__device__ __forceinline__ float bfhi(uint v) { return __uint_as_float(v & 0xffff0000u); }
__device__ __forceinline__ uint bfr(float x) {
  uint u = __float_as_uint(x);
  return (u + 0x7fffu + ((u >> 16) & 1u)) >> 16;
}
__device__ __forceinline__ uint packbf(float lo, float hi) { return bfr(lo) | (bfr(hi) << 16); }

// ---- degree count over col (self loops added analytically: deg+1) ----
__global__ void count_deg(const int* __restrict__ col, int* __restrict__ deg, int e) {
  int i = blockIdx.x * 256 + threadIdx.x;
  if (i < e) {
    int c = __builtin_nontemporal_load(&col[i]);
    atomicAdd(&deg[c], 1);
  }
}

// ---- scan1 also emits dinv (fused deg_to_dinv) ----
__global__ __launch_bounds__(1024) void scan1(const int* __restrict__ deg,
    int* __restrict__ cur, int* __restrict__ bsum, float* __restrict__ dinv, int n) {
  __shared__ int s[1024];
  int tid = threadIdx.x;
  int i = blockIdx.x * 1024 + tid;
  int v = (i < n) ? deg[i] : 0;
  if (i < n) dinv[i] = rsqrtf((float)v + 1.0f);
  s[tid] = v;
  __syncthreads();
  for (int off = 1; off < 1024; off <<= 1) {
    int t = (tid >= off) ? s[tid - off] : 0;
    __syncthreads();
    s[tid] += t;
    __syncthreads();
  }
  if (i < n) cur[i] = s[tid] - v;
  if (tid == 1023) bsum[blockIdx.x] = s[1023];
}

__global__ void scan2(int* __restrict__ bsum, int nb) {
  if (threadIdx.x == 0 && blockIdx.x == 0) {
    int acc = 0;
    for (int b = 0; b < nb; ++b) { int t = bsum[b]; bsum[b] = acc; acc += t; }
  }
}

// ---- scan3 also emits bin cursors (fused init_bins) ----
__global__ void scan3(int* __restrict__ cur, const int* __restrict__ bsum,
                      int* __restrict__ bcur, int n) {
  int i = blockIdx.x * 256 + threadIdx.x;
  if (i < n) {
    int val = cur[i] + bsum[i >> 10];
    cur[i] = val;
    if ((i & 255) == 0) bcur[i >> 8] = val;
  }
}

// ---- pass1: coarse-bin edges; col cached in registers across both phases ----
__global__ __launch_bounds__(256) void pass1_bin(const int* __restrict__ row,
    const int* __restrict__ col, int* __restrict__ bin_cursor,
    uint* __restrict__ temp, int e) {
  __shared__ int hist[NBINS];
  __shared__ int base[NBINS];
  int tid = threadIdx.x;
  int s = blockIdx.x * CH;
  int colr[32];
  #pragma unroll
  for (int it = 0; it < 32; ++it) {
    int i = s + tid + it * 256;
    colr[it] = (i < e) ? __builtin_nontemporal_load(&col[i]) : -1;
  }
  for (int i = tid; i < NBINS; i += 256) hist[i] = 0;
  __syncthreads();
  #pragma unroll
  for (int it = 0; it < 32; ++it)
    if (colr[it] >= 0) atomicAdd(&hist[colr[it] >> 8], 1);
  __syncthreads();
  for (int i = tid; i < NBINS; i += 256) {
    int cnt = hist[i];
    base[i] = cnt ? atomicAdd(&bin_cursor[i], cnt) : 0;
    hist[i] = 0;                       // reuse as rank counter
  }
  __syncthreads();
  #pragma unroll
  for (int it = 0; it < 32; ++it) {
    int c = colr[it];
    if (c >= 0) {
      int i = s + tid + it * 256;
      int r = __builtin_nontemporal_load(&row[i]);
      int b = c >> 8;
      int pos = base[b] + atomicAdd(&hist[b], 1);
      temp[pos] = ((uint)r << 8) | (uint)(c & 255);
    }
  }
}

// ---- pass2: one block per bin; permute bin slice to exact CSC positions ----
__global__ __launch_bounds__(256) void pass2_scatter(const uint* __restrict__ temp,
    const int* __restrict__ cursor0, int* __restrict__ csr, int n, int e) {
  __shared__ int cur[256];
  int b = blockIdx.x;
  int nb = b * 256;
  int tid = threadIdx.x;
  if (nb + tid < n) cur[tid] = cursor0[nb + tid];
  __syncthreads();
  int s = cursor0[nb];
  int eend = (nb + 256 >= n) ? e : cursor0[nb + 256];
  for (int i = s + tid; i < eend; i += 256) {
    uint rec = __builtin_nontemporal_load(&temp[i]);
    int pos = atomicAdd(&cur[rec & 255u], 1);
    csr[pos] = (int)(rec >> 8);
  }
}

// g1 = glob_init @ w + b   (64 threads)
__global__ void glob1_kernel(const float* __restrict__ gi, const float* __restrict__ w,
                             const float* __restrict__ b, float* __restrict__ out) {
  int j = threadIdx.x;
  float acc = b[j];
  for (int k = 0; k < 64; ++k) acc += gi[k] * w[k * 64 + j];
  out[j] = acc;
}

// ---- gemm1: h1' = dinv * (x @ w_nn1 + b_nn1 + g1), bf16-packed [N][32] ----
__global__ __launch_bounds__(256) void gemm1(const float* __restrict__ x,
    const float* __restrict__ w, const float* __restrict__ b,
    const float* __restrict__ g1, const float* __restrict__ dinv,
    uint* __restrict__ hbf, int n) {
  __shared__ float XsT[FIN][64];   // [k][r^swz] 32 KB
  __shared__ float Ws[FIN][DD];    // [k][j]     32 KB
  int base = blockIdx.x * 64;
  const float4* w4 = (const float4*)w;
  float4* ws4 = (float4*)Ws;
  for (int idx = threadIdx.x; idx < FIN * DD / 4; idx += 256) ws4[idx] = w4[idx];
  const float4* x4 = (const float4*)x;
  for (int idx = threadIdx.x; idx < 64 * FIN / 4; idx += 256) {
    int kq = idx & 31, r = idx >> 5;
    int gr = base + r;
    float4 v = make_float4(0.f, 0.f, 0.f, 0.f);
    if (gr < n) v = x4[gr * 32 + kq];
    int k0 = kq * 4, s = k0 & 60;
    XsT[k0 + 0][r ^ s] = v.x;
    XsT[k0 + 1][r ^ s] = v.y;
    XsT[k0 + 2][r ^ s] = v.z;
    XsT[k0 + 3][r ^ s] = v.w;
  }
  __syncthreads();
  int tx = threadIdx.x & 15, ty = threadIdx.x >> 4;
  float acc[4][4] = {};
  #pragma unroll 4
  for (int k = 0; k < FIN; ++k) {
    float4 av = *(const float4*)&XsT[k][(4 * ty) ^ (k & 60)];
    float4 bv = *(const float4*)&Ws[k][4 * tx];
    float ax[4] = {av.x, av.y, av.z, av.w};
    float bx[4] = {bv.x, bv.y, bv.z, bv.w};
    #pragma unroll
    for (int i = 0; i < 4; ++i)
      #pragma unroll
      for (int j = 0; j < 4; ++j)
        acc[i][j] += ax[i] * bx[j];
  }
  float bias[4];
  #pragma unroll
  for (int j = 0; j < 4; ++j) bias[j] = b[4 * tx + j] + g1[4 * tx + j];
  #pragma unroll
  for (int i = 0; i < 4; ++i) {
    int row = base + 4 * ty + i;
    if (row < n) {
      float dv = dinv[row];
      hbf[row * 32 + 2 * tx]     = packbf(dv * (acc[i][0] + bias[0]), dv * (acc[i][1] + bias[1]));
      hbf[row * 32 + 2 * tx + 1] = packbf(dv * (acc[i][2] + bias[2]), dv * (acc[i][3] + bias[3]));
    }
  }
}

// ---- gemm2: h2' = dinv * (relu(agg1) @ w_nn2 + b_nn2 + globs2[gidx]), bf16 ----
__global__ __launch_bounds__(256) void gemm2(const uint* __restrict__ hbf,
    const float* __restrict__ w, const float* __restrict__ bb,
    const float* __restrict__ globs2, const int* __restrict__ gidx,
    const float* __restrict__ dinv, uint* __restrict__ obf, int n) {
  __shared__ float XsT[DD][64];    // 16 KB
  __shared__ float Ws[DD][DD];     // 16 KB
  int base = blockIdx.x * 64;
  const float4* w4 = (const float4*)w;
  float4* ws4 = (float4*)Ws;
  for (int idx = threadIdx.x; idx < DD * DD / 4; idx += 256) ws4[idx] = w4[idx];
  const uint2* h2 = (const uint2*)hbf;
  for (int idx = threadIdx.x; idx < 64 * DD / 4; idx += 256) {
    int kq = idx & 15, r = idx >> 4;
    int gr = base + r;
    uint2 v = make_uint2(0u, 0u);
    if (gr < n) v = h2[gr * 16 + kq];
    int k0 = kq * 4, s = k0 & 60;
    XsT[k0 + 0][r ^ s] = fmaxf(bflo(v.x), 0.f);
    XsT[k0 + 1][r ^ s] = fmaxf(bfhi(v.x), 0.f);
    XsT[k0 + 2][r ^ s] = fmaxf(bflo(v.y), 0.f);
    XsT[k0 + 3][r ^ s] = fmaxf(bfhi(v.y), 0.f);
  }
  __syncthreads();
  int tx = threadIdx.x & 15, ty = threadIdx.x >> 4;
  float acc[4][4] = {};
  #pragma unroll 4
  for (int k = 0; k < DD; ++k) {
    float4 av = *(const float4*)&XsT[k][(4 * ty) ^ (k & 60)];
    float4 bv = *(const float4*)&Ws[k][4 * tx];
    float ax[4] = {av.x, av.y, av.z, av.w};
    float bx[4] = {bv.x, bv.y, bv.z, bv.w};
    #pragma unroll
    for (int i = 0; i < 4; ++i)
      #pragma unroll
      for (int j = 0; j < 4; ++j)
        acc[i][j] += ax[i] * bx[j];
  }
  #pragma unroll
  for (int i = 0; i < 4; ++i) {
    int row = base + 4 * ty + i;
    if (row < n) {
      const float* gl = globs2 + gidx[row] * 64 + 4 * tx;
      float dv = dinv[row];
      float c0 = acc[i][0] + bb[4 * tx + 0] + gl[0];
      float c1 = acc[i][1] + bb[4 * tx + 1] + gl[1];
      float c2 = acc[i][2] + bb[4 * tx + 2] + gl[2];
      float c3 = acc[i][3] + bb[4 * tx + 3] + gl[3];
      obf[row * 32 + 2 * tx]     = packbf(dv * c0, dv * c1);
      obf[row * 32 + 2 * tx + 1] = packbf(dv * c2, dv * c3);
    }
  }
}

// ---- pull-gather: out[c] = dinv[c] * (sum_e h'[src_e] + h'[c]).
// One wave per node; halves take even/odd edges; ILP 8 per half.
template <int SIG>
__global__ __launch_bounds__(256) void gather_agg(const int* __restrict__ csr,
    const int* __restrict__ cursor0, const int* __restrict__ deg,
    const float* __restrict__ dinv, const uint* __restrict__ h,
    void* __restrict__ outv, int n) {
  int node = blockIdx.x * 4 + (threadIdx.x >> 6);
  if (node >= n) return;
  int lane = threadIdx.x & 63;
  int half = lane >> 5, fp = lane & 31;
  int start = cursor0[node];
  int end = start + deg[node];
  float a0 = 0.f, a1 = 0.f;
  int e = start + half;
  for (; e + 14 < end; e += 16) {      // 8 edges in flight per half
    int r0 = __builtin_nontemporal_load(&csr[e]);
    int r1 = __builtin_nontemporal_load(&csr[e + 2]);
    int r2 = __builtin_nontemporal_load(&csr[e + 4]);
    int r3 = __builtin_nontemporal_load(&csr[e + 6]);
    int r4 = __builtin_nontemporal_load(&csr[e + 8]);
    int r5 = __builtin_nontemporal_load(&csr[e + 10]);
    int r6 = __builtin_nontemporal_load(&csr[e + 12]);
    int r7 = __builtin_nontemporal_load(&csr[e + 14]);
    uint h0 = h[r0 * 32 + fp];
    uint h1 = h[r1 * 32 + fp];
    uint h2 = h[r2 * 32 + fp];
    uint h3 = h[r3 * 32 + fp];
    uint h4 = h[r4 * 32 + fp];
    uint h5 = h[r5 * 32 + fp];
    uint h6 = h[r6 * 32 + fp];
    uint h7 = h[r7 * 32 + fp];
    a0 += bflo(h0) + bflo(h1) + bflo(h2) + bflo(h3)
        + bflo(h4) + bflo(h5) + bflo(h6) + bflo(h7);
    a1 += bfhi(h0) + bfhi(h1) + bfhi(h2) + bfhi(h3)
        + bfhi(h4) + bfhi(h5) + bfhi(h6) + bfhi(h7);
  }
  for (; e < end; e += 2) {
    int r0 = __builtin_nontemporal_load(&csr[e]);
    uint h0 = h[r0 * 32 + fp];
    a0 += bflo(h0);
    a1 += bfhi(h0);
  }
  if (half == 0) {                     // self loop: + h'[c]
    uint hv = h[node * 32 + fp];
    a0 += bflo(hv);
    a1 += bfhi(hv);
  }
  a0 += __shfl(a0, lane ^ 32);
  a1 += __shfl(a1, lane ^ 32);
  if (half == 0) {
    float di = dinv[node];
    a0 *= di;
    a1 *= di;
    if (SIG) {
      float2 o;
      o.x = 1.f / (1.f + __expf(-a0));
      o.y = 1.f / (1.f + __expf(-a1));
      ((float2*)outv)[node * 32 + fp] = o;
    } else {
      ((uint*)outv)[node * 32 + fp] = packbf(a0, a1);
    }
  }
}

// chunked segment-max over sorted graph_indices; bf16 input
__global__ void seg_max(const ushort* __restrict__ B, const int* __restrict__ gidx,
                        unsigned* __restrict__ parts_ord, int n, int chunk) {
  int f = threadIdx.x;
  int start = blockIdx.x * chunk;
  int end = start + chunk; if (end > n) end = n;
  if (start >= end) return;
  int curg = gidx[start];
  float m = -INFINITY;
  for (int i = start; i < end; ++i) {
    int g = gidx[i];
    if (g != curg) {
      atomicMax(&parts_ord[curg * 64 + f], f2ord(m));
      curg = g; m = -INFINITY;
    }
    m = fmaxf(m, __uint_as_float(((uint)B[i * 64 + f]) << 16));
  }
  atomicMax(&parts_ord[curg * 64 + f], f2ord(m));
}

// globs2[g] = ((glob_init@w_gg1 + b_gg1 + parts[g]@w_ng1 + b_ng1) @ w_gn2 + b_gn2)
__global__ void glob2_kernel(const float* __restrict__ gi, const unsigned* __restrict__ parts_ord,
    const float* __restrict__ w_gg1, const float* __restrict__ b_gg1,
    const float* __restrict__ w_ng1, const float* __restrict__ b_ng1,
    const float* __restrict__ w_gn2, const float* __restrict__ b_gn2,
    float* __restrict__ globs2) {
  __shared__ float t[64];
  int g = blockIdx.x, j = threadIdx.x;
  float acc = b_gg1[j] + b_ng1[j];
  for (int k = 0; k < 64; ++k) acc += gi[k] * w_gg1[k * 64 + j];
  for (int k = 0; k < 64; ++k) acc += ord2f(parts_ord[g * 64 + k]) * w_ng1[k * 64 + j];
  t[j] = acc;
  __syncthreads();
  float acc2 = b_gn2[j];
  for (int k = 0; k < 64; ++k) acc2 += t[k] * w_gn2[k * 64 + j];
  globs2[g * 64 + j] = acc2;
}

extern "C" void kernel_launch(void* const* d_in, const int* in_sizes, int n_in,
                              void* d_out, int out_size, void* d_ws, size_t ws_size,
                              hipStream_t stream) {
  const float* x         = (const float*)d_in[0];
  const int*   ei        = (const int*)d_in[1];
  const int*   gidx      = (const int*)d_in[2];
  const float* glob_init = (const float*)d_in[3];
  const float* w_nn1 = (const float*)d_in[4];  const float* b_nn1 = (const float*)d_in[5];
  const float* w_gn1 = (const float*)d_in[6];  const float* b_gn1 = (const float*)d_in[7];
  const float* w_gg1 = (const float*)d_in[8];  const float* b_gg1 = (const float*)d_in[9];
  const float* w_ng1 = (const float*)d_in[10]; const float* b_ng1 = (const float*)d_in[11];
  const float* w_nn2 = (const float*)d_in[12]; const float* b_nn2 = (const float*)d_in[13];
  const float* w_gn2 = (const float*)d_in[14]; const float* b_gn2 = (const float*)d_in[15];
  // w_gg2/b_gg2/w_ng2/b_ng2 are dead: layer-2 glob output is discarded.

  const int* row = ei;           // edge_index[0]
  const int* col = ei + EE;      // edge_index[1]

  // ---- workspace layout (256-aligned) ----
  char* p = (char*)d_ws;
  int*      deg    = (int*)p;       p += ((NN * 4 + 255) & ~255);
  float*    dinv   = (float*)p;     p += ((NN * 4 + 255) & ~255);
  int*      cursor = (int*)p;       p += ((NN * 4 + 255) & ~255);   // cursor0: CSC starts
  int*      bsum   = (int*)p;       p += 1024;
  int*      bcur   = (int*)p;       p += ((NBINS * 4 + 255) & ~255);
  uint*     temp   = (uint*)p;      p += (size_t)EE * 4;            // binned records
  int*      csr    = (int*)p;       p += (size_t)EE * 4;            // final CSC (src only)
  uint*     A      = (uint*)p;      p += (size_t)NN * 32 * 4;       // bf16 h' buffer
  unsigned* parts  = (unsigned*)p;  p += NG * 64 * 4;
  float*    g1     = (float*)p;     p += 256;
  float*    globs2 = (float*)p;
  uint*     B      = (uint*)d_out;  // bf16 agg1 buffer in d_out (overwritten by final out)
  float*    out    = (float*)d_out;

  const int NB = (NN + 1023) / 1024;

  // ---- CSC build (shared by both layers) ----
  hipMemsetAsync(deg, 0, NN * 4, stream);
  count_deg<<<(EE + 255) / 256, 256, 0, stream>>>(col, deg, EE);
  scan1<<<NB, 1024, 0, stream>>>(deg, cursor, bsum, dinv, NN);
  scan2<<<1, 64, 0, stream>>>(bsum, NB);
  scan3<<<(NN + 255) / 256, 256, 0, stream>>>(cursor, bsum, bcur, NN);
  pass1_bin<<<(EE + CH - 1) / CH, 256, 0, stream>>>(row, col, bcur, temp, EE);
  pass2_scatter<<<NBINS, 256, 0, stream>>>(temp, cursor, csr, NN, EE);

  // ---- layer 1 ----
  glob1_kernel<<<1, 64, 0, stream>>>(glob_init, w_gn1, b_gn1, g1);
  gemm1<<<(NN + 63) / 64, 256, 0, stream>>>(x, w_nn1, b_nn1, g1, dinv, A, NN);
  gather_agg<0><<<(NN + 3) / 4, 256, 0, stream>>>(csr, cursor, deg, dinv, A, (void*)B, NN);

  // readout -> per-graph globals for layer 2
  hipMemsetAsync(parts, 0, NG * 64 * 4, stream);
  seg_max<<<(NN + 63) / 64, 64, 0, stream>>>((const ushort*)B, gidx, parts, NN, 64);
  glob2_kernel<<<NG, 64, 0, stream>>>(glob_init, parts, w_gg1, b_gg1, w_ng1, b_ng1,
                                      w_gn2, b_gn2, globs2);

  // ---- layer 2 (glob output discarded by reference) ----
  gemm2<<<(NN + 63) / 64, 256, 0, stream>>>(B, w_nn2, b_nn2, globs2, gidx, dinv, A, NN);
  gather_agg<1><<<(NN + 3) / 4, 256, 0, stream>>>(csr, cursor, deg, dinv, A, (void*)out, NN);
}

// Round 8
// 272.150 us; speedup vs baseline: 1.3902x; 1.3902x over previous
//
#include <hip/hip_runtime.h>
#include <math.h>

#define NN 100000
#define EE 1600000
#define FIN 128
#define DD 64
#define NG 64
#define NBINS ((NN + 255) / 256)   // 391 bins of 256 dst nodes
#define CH 8192                    // edges per pass1 block (= 256 threads * 32)
#define HCH 8192                   // edges per bin_hist block

typedef unsigned int uint;
typedef unsigned short ushort;

// ---- ordered-float <-> uint mapping for atomicMax on floats ----
__device__ __forceinline__ unsigned f2ord(float f) {
  unsigned u = __float_as_uint(f);
  return (u & 0x80000000u) ? ~u : (u | 0x80000000u);
}
__device__ __forceinline__ float ord2f(unsigned m) {
  unsigned u = (m & 0x80000000u) ? (m & 0x7FFFFFFFu) : ~m;
  return __uint_as_float(u);
}
// ---- bf16 helpers (fp32 accumulate everywhere; RNE pack) ----
__device__ __forceinline__ float bflo(uint v) { return __uint_as_float(v << 16); }
__device__ __forceinline__ float bfhi(uint v) { return __uint_as_float(v & 0xffff0000u); }
__device__ __forceinline__ uint bfr(float x) {
  uint u = __float_as_uint(x);
  return (u + 0x7fffu + ((u >> 16) & 1u)) >> 16;
}
__device__ __forceinline__ uint packbf(float lo, float hi) { return bfr(lo) | (bfr(hi) << 16); }

// ---- bin-level histogram (LDS-staged; ~391 global atomics per block) ----
__global__ __launch_bounds__(256) void bin_hist(const int* __restrict__ col,
                                                int* __restrict__ bin_cnt, int e) {
  __shared__ int hist[NBINS];
  int tid = threadIdx.x;
  for (int i = tid; i < NBINS; i += 256) hist[i] = 0;
  __syncthreads();
  int s = blockIdx.x * HCH;
  int eend = s + HCH < e ? s + HCH : e;
  for (int i = s + tid; i < eend; i += 256) {
    int c = __builtin_nontemporal_load(&col[i]);
    atomicAdd(&hist[c >> 8], 1);
  }
  __syncthreads();
  for (int i = tid; i < NBINS; i += 256)
    if (hist[i]) atomicAdd(&bin_cnt[i], hist[i]);
}

// ---- scan 391 bin counts -> bstart (exclusive, +sentinel) and bcur ----
__global__ __launch_bounds__(512) void bin_scan(const int* __restrict__ bin_cnt,
    int* __restrict__ bstart, int* __restrict__ bcur) {
  __shared__ int s[512];
  int tid = threadIdx.x;
  int v = (tid < NBINS) ? bin_cnt[tid] : 0;
  s[tid] = v;
  __syncthreads();
  for (int off = 1; off < 512; off <<= 1) {
    int t = (tid >= off) ? s[tid - off] : 0;
    __syncthreads();
    s[tid] += t;
    __syncthreads();
  }
  if (tid < NBINS) {
    int st = s[tid] - v;
    bstart[tid] = st;
    bcur[tid] = st;
  }
  if (tid == NBINS - 1) bstart[NBINS] = s[tid];
}

// ---- pass1: coarse-bin edges; col cached in registers across both phases ----
__global__ __launch_bounds__(256) void pass1_bin(const int* __restrict__ row,
    const int* __restrict__ col, int* __restrict__ bin_cursor,
    uint* __restrict__ temp, int e) {
  __shared__ int hist[NBINS];
  __shared__ int base[NBINS];
  int tid = threadIdx.x;
  int s = blockIdx.x * CH;
  int colr[32];
  #pragma unroll
  for (int it = 0; it < 32; ++it) {
    int i = s + tid + it * 256;
    colr[it] = (i < e) ? __builtin_nontemporal_load(&col[i]) : -1;
  }
  for (int i = tid; i < NBINS; i += 256) hist[i] = 0;
  __syncthreads();
  #pragma unroll
  for (int it = 0; it < 32; ++it)
    if (colr[it] >= 0) atomicAdd(&hist[colr[it] >> 8], 1);
  __syncthreads();
  for (int i = tid; i < NBINS; i += 256) {
    int cnt = hist[i];
    base[i] = cnt ? atomicAdd(&bin_cursor[i], cnt) : 0;
    hist[i] = 0;                       // reuse as rank counter
  }
  __syncthreads();
  #pragma unroll
  for (int it = 0; it < 32; ++it) {
    int c = colr[it];
    if (c >= 0) {
      int i = s + tid + it * 256;
      int r = __builtin_nontemporal_load(&row[i]);
      int b = c >> 8;
      int pos = base[b] + atomicAdd(&hist[b], 1);
      temp[pos] = ((uint)r << 8) | (uint)(c & 255);
    }
  }
}

// ---- pass2: one block per bin. Derives per-node deg/cursor0/dinv from the
// bin's LDS histogram (kills the global count_deg + 100K scan), then permutes
// the bin slice to exact CSC positions (block-private ~16 KB write region).
__global__ __launch_bounds__(256) void pass2_scatter(const uint* __restrict__ temp,
    const int* __restrict__ bstart, int* __restrict__ cursor0,
    int* __restrict__ deg, float* __restrict__ dinv,
    int* __restrict__ csr, int n) {
  __shared__ int hist[256];
  __shared__ int sc[256];
  __shared__ int cur[256];
  int b = blockIdx.x;
  int tid = threadIdx.x;
  int s = bstart[b], eend = bstart[b + 1];
  hist[tid] = 0;
  __syncthreads();
  for (int i = s + tid; i < eend; i += 256)
    atomicAdd(&hist[temp[i] & 255u], 1);
  __syncthreads();
  int v = hist[tid];
  sc[tid] = v;
  __syncthreads();
  for (int off = 1; off < 256; off <<= 1) {
    int t = (tid >= off) ? sc[tid - off] : 0;
    __syncthreads();
    sc[tid] += t;
    __syncthreads();
  }
  int st = s + sc[tid] - v;            // exclusive within bin + bin base
  cur[tid] = st;
  int node = b * 256 + tid;
  if (node < n) {
    cursor0[node] = st;
    deg[node] = v;
    dinv[node] = rsqrtf((float)v + 1.0f);
  }
  __syncthreads();
  for (int i = s + tid; i < eend; i += 256) {
    uint rec = temp[i];                // L2-warm from histogram pass
    int pos = atomicAdd(&cur[rec & 255u], 1);
    csr[pos] = (int)(rec >> 8);
  }
}

// g1 = glob_init @ w + b   (64 threads)
__global__ void glob1_kernel(const float* __restrict__ gi, const float* __restrict__ w,
                             const float* __restrict__ b, float* __restrict__ out) {
  int j = threadIdx.x;
  float acc = b[j];
  for (int k = 0; k < 64; ++k) acc += gi[k] * w[k * 64 + j];
  out[j] = acc;
}

// ---- gemm1: h1' = dinv * (x @ w_nn1 + b_nn1 + g1), bf16-packed [N][32] ----
__global__ __launch_bounds__(256) void gemm1(const float* __restrict__ x,
    const float* __restrict__ w, const float* __restrict__ b,
    const float* __restrict__ g1, const float* __restrict__ dinv,
    uint* __restrict__ hbf, int n) {
  __shared__ float XsT[FIN][64];   // [k][r^swz] 32 KB
  __shared__ float Ws[FIN][DD];    // [k][j]     32 KB
  int base = blockIdx.x * 64;
  const float4* w4 = (const float4*)w;
  float4* ws4 = (float4*)Ws;
  for (int idx = threadIdx.x; idx < FIN * DD / 4; idx += 256) ws4[idx] = w4[idx];
  const float4* x4 = (const float4*)x;
  for (int idx = threadIdx.x; idx < 64 * FIN / 4; idx += 256) {
    int kq = idx & 31, r = idx >> 5;
    int gr = base + r;
    float4 v = make_float4(0.f, 0.f, 0.f, 0.f);
    if (gr < n) v = x4[gr * 32 + kq];
    int k0 = kq * 4, s = k0 & 60;
    XsT[k0 + 0][r ^ s] = v.x;
    XsT[k0 + 1][r ^ s] = v.y;
    XsT[k0 + 2][r ^ s] = v.z;
    XsT[k0 + 3][r ^ s] = v.w;
  }
  __syncthreads();
  int tx = threadIdx.x & 15, ty = threadIdx.x >> 4;
  float acc[4][4] = {};
  #pragma unroll 4
  for (int k = 0; k < FIN; ++k) {
    float4 av = *(const float4*)&XsT[k][(4 * ty) ^ (k & 60)];
    float4 bv = *(const float4*)&Ws[k][4 * tx];
    float ax[4] = {av.x, av.y, av.z, av.w};
    float bx[4] = {bv.x, bv.y, bv.z, bv.w};
    #pragma unroll
    for (int i = 0; i < 4; ++i)
      #pragma unroll
      for (int j = 0; j < 4; ++j)
        acc[i][j] += ax[i] * bx[j];
  }
  float bias[4];
  #pragma unroll
  for (int j = 0; j < 4; ++j) bias[j] = b[4 * tx + j] + g1[4 * tx + j];
  #pragma unroll
  for (int i = 0; i < 4; ++i) {
    int row = base + 4 * ty + i;
    if (row < n) {
      float dv = dinv[row];
      hbf[row * 32 + 2 * tx]     = packbf(dv * (acc[i][0] + bias[0]), dv * (acc[i][1] + bias[1]));
      hbf[row * 32 + 2 * tx + 1] = packbf(dv * (acc[i][2] + bias[2]), dv * (acc[i][3] + bias[3]));
    }
  }
}

// ---- gemm2: h2' = dinv * (relu(agg1) @ w_nn2 + b_nn2 + globs2[gidx]), bf16 ----
__global__ __launch_bounds__(256) void gemm2(const uint* __restrict__ hbf,
    const float* __restrict__ w, const float* __restrict__ bb,
    const float* __restrict__ globs2, const int* __restrict__ gidx,
    const float* __restrict__ dinv, uint* __restrict__ obf, int n) {
  __shared__ float XsT[DD][64];    // 16 KB
  __shared__ float Ws[DD][DD];     // 16 KB
  int base = blockIdx.x * 64;
  const float4* w4 = (const float4*)w;
  float4* ws4 = (float4*)Ws;
  for (int idx = threadIdx.x; idx < DD * DD / 4; idx += 256) ws4[idx] = w4[idx];
  const uint2* h2 = (const uint2*)hbf;
  for (int idx = threadIdx.x; idx < 64 * DD / 4; idx += 256) {
    int kq = idx & 15, r = idx >> 4;
    int gr = base + r;
    uint2 v = make_uint2(0u, 0u);
    if (gr < n) v = h2[gr * 16 + kq];
    int k0 = kq * 4, s = k0 & 60;
    XsT[k0 + 0][r ^ s] = fmaxf(bflo(v.x), 0.f);
    XsT[k0 + 1][r ^ s] = fmaxf(bfhi(v.x), 0.f);
    XsT[k0 + 2][r ^ s] = fmaxf(bflo(v.y), 0.f);
    XsT[k0 + 3][r ^ s] = fmaxf(bfhi(v.y), 0.f);
  }
  __syncthreads();
  int tx = threadIdx.x & 15, ty = threadIdx.x >> 4;
  float acc[4][4] = {};
  #pragma unroll 4
  for (int k = 0; k < DD; ++k) {
    float4 av = *(const float4*)&XsT[k][(4 * ty) ^ (k & 60)];
    float4 bv = *(const float4*)&Ws[k][4 * tx];
    float ax[4] = {av.x, av.y, av.z, av.w};
    float bx[4] = {bv.x, bv.y, bv.z, bv.w};
    #pragma unroll
    for (int i = 0; i < 4; ++i)
      #pragma unroll
      for (int j = 0; j < 4; ++j)
        acc[i][j] += ax[i] * bx[j];
  }
  #pragma unroll
  for (int i = 0; i < 4; ++i) {
    int row = base + 4 * ty + i;
    if (row < n) {
      const float* gl = globs2 + gidx[row] * 64 + 4 * tx;
      float dv = dinv[row];
      float c0 = acc[i][0] + bb[4 * tx + 0] + gl[0];
      float c1 = acc[i][1] + bb[4 * tx + 1] + gl[1];
      float c2 = acc[i][2] + bb[4 * tx + 2] + gl[2];
      float c3 = acc[i][3] + bb[4 * tx + 3] + gl[3];
      obf[row * 32 + 2 * tx]     = packbf(dv * c0, dv * c1);
      obf[row * 32 + 2 * tx + 1] = packbf(dv * c2, dv * c3);
    }
  }
}

// ---- pull-gather: out[c] = dinv[c] * (sum_e h'[src_e] + h'[c]).
// One wave per node; halves take even/odd edges. PREDICATED ILP-8: indices
// clamped to end-1 (duplicate loads hit the same L1 line), accumulate masked.
// Every edge, including the last partial group, is covered by 8-deep batches.
template <int SIG>
__global__ __launch_bounds__(256) void gather_agg(const int* __restrict__ csr,
    const int* __restrict__ cursor0, const int* __restrict__ deg,
    const float* __restrict__ dinv, const uint* __restrict__ h,
    void* __restrict__ outv, int n) {
  int node = blockIdx.x * 4 + (threadIdx.x >> 6);
  if (node >= n) return;
  int lane = threadIdx.x & 63;
  int half = lane >> 5, fp = lane & 31;
  int start = cursor0[node];
  int end = start + deg[node];
  int last = end - 1;
  float a0 = 0.f, a1 = 0.f;
  for (int e = start + half; e < end; e += 16) {
    uint hv[8];
    int idx[8];
    #pragma unroll
    for (int j = 0; j < 8; ++j) {
      int i = e + 2 * j;
      idx[j] = i;
      int ic = i < last ? i : last;
      int r = __builtin_nontemporal_load(&csr[ic]);
      hv[j] = h[r * 32 + fp];
    }
    #pragma unroll
    for (int j = 0; j < 8; ++j) {
      float m0 = (idx[j] < end) ? bflo(hv[j]) : 0.f;
      float m1 = (idx[j] < end) ? bfhi(hv[j]) : 0.f;
      a0 += m0;
      a1 += m1;
    }
  }
  if (half == 0) {                     // self loop: + h'[c]
    uint hvv = h[node * 32 + fp];
    a0 += bflo(hvv);
    a1 += bfhi(hvv);
  }
  a0 += __shfl(a0, lane ^ 32);
  a1 += __shfl(a1, lane ^ 32);
  if (half == 0) {
    float di = dinv[node];
    a0 *= di;
    a1 *= di;
    if (SIG) {
      float2 o;
      o.x = 1.f / (1.f + __expf(-a0));
      o.y = 1.f / (1.f + __expf(-a1));
      ((float2*)outv)[node * 32 + fp] = o;
    } else {
      ((uint*)outv)[node * 32 + fp] = packbf(a0, a1);
    }
  }
}

// chunked segment-max over sorted graph_indices; bf16 input
__global__ void seg_max(const ushort* __restrict__ B, const int* __restrict__ gidx,
                        unsigned* __restrict__ parts_ord, int n, int chunk) {
  int f = threadIdx.x;
  int start = blockIdx.x * chunk;
  int end = start + chunk; if (end > n) end = n;
  if (start >= end) return;
  int curg = gidx[start];
  float m = -INFINITY;
  for (int i = start; i < end; ++i) {
    int g = gidx[i];
    if (g != curg) {
      atomicMax(&parts_ord[curg * 64 + f], f2ord(m));
      curg = g; m = -INFINITY;
    }
    m = fmaxf(m, __uint_as_float(((uint)B[i * 64 + f]) << 16));
  }
  atomicMax(&parts_ord[curg * 64 + f], f2ord(m));
}

// globs2[g] = ((glob_init@w_gg1 + b_gg1 + parts[g]@w_ng1 + b_ng1) @ w_gn2 + b_gn2)
__global__ void glob2_kernel(const float* __restrict__ gi, const unsigned* __restrict__ parts_ord,
    const float* __restrict__ w_gg1, const float* __restrict__ b_gg1,
    const float* __restrict__ w_ng1, const float* __restrict__ b_ng1,
    const float* __restrict__ w_gn2, const float* __restrict__ b_gn2,
    float* __restrict__ globs2) {
  __shared__ float t[64];
  int g = blockIdx.x, j = threadIdx.x;
  float acc = b_gg1[j] + b_ng1[j];
  for (int k = 0; k < 64; ++k) acc += gi[k] * w_gg1[k * 64 + j];
  for (int k = 0; k < 64; ++k) acc += ord2f(parts_ord[g * 64 + k]) * w_ng1[k * 64 + j];
  t[j] = acc;
  __syncthreads();
  float acc2 = b_gn2[j];
  for (int k = 0; k < 64; ++k) acc2 += t[k] * w_gn2[k * 64 + j];
  globs2[g * 64 + j] = acc2;
}

extern "C" void kernel_launch(void* const* d_in, const int* in_sizes, int n_in,
                              void* d_out, int out_size, void* d_ws, size_t ws_size,
                              hipStream_t stream) {
  const float* x         = (const float*)d_in[0];
  const int*   ei        = (const int*)d_in[1];
  const int*   gidx      = (const int*)d_in[2];
  const float* glob_init = (const float*)d_in[3];
  const float* w_nn1 = (const float*)d_in[4];  const float* b_nn1 = (const float*)d_in[5];
  const float* w_gn1 = (const float*)d_in[6];  const float* b_gn1 = (const float*)d_in[7];
  const float* w_gg1 = (const float*)d_in[8];  const float* b_gg1 = (const float*)d_in[9];
  const float* w_ng1 = (const float*)d_in[10]; const float* b_ng1 = (const float*)d_in[11];
  const float* w_nn2 = (const float*)d_in[12]; const float* b_nn2 = (const float*)d_in[13];
  const float* w_gn2 = (const float*)d_in[14]; const float* b_gn2 = (const float*)d_in[15];
  // w_gg2/b_gg2/w_ng2/b_ng2 are dead: layer-2 glob output is discarded.

  const int* row = ei;           // edge_index[0]
  const int* col = ei + EE;      // edge_index[1]

  // ---- workspace layout (256-aligned) ----
  char* p = (char*)d_ws;
  int*      deg    = (int*)p;       p += ((NN * 4 + 255) & ~255);
  float*    dinv   = (float*)p;     p += ((NN * 4 + 255) & ~255);
  int*      cursor = (int*)p;       p += ((NN * 4 + 255) & ~255);   // cursor0: CSC starts
  int*      bcnt   = (int*)p;       p += ((NBINS * 4 + 255) & ~255);
  int*      bstart = (int*)p;       p += (((NBINS + 1) * 4 + 255) & ~255);
  int*      bcur   = (int*)p;       p += ((NBINS * 4 + 255) & ~255);
  uint*     temp   = (uint*)p;      p += (size_t)EE * 4;            // binned records
  int*      csr    = (int*)p;       p += (size_t)EE * 4;            // final CSC (src only)
  uint*     A      = (uint*)p;      p += (size_t)NN * 32 * 4;       // bf16 h' buffer
  unsigned* parts  = (unsigned*)p;  p += NG * 64 * 4;
  float*    g1     = (float*)p;     p += 256;
  float*    globs2 = (float*)p;
  uint*     B      = (uint*)d_out;  // bf16 agg1 buffer in d_out (overwritten by final out)
  float*    out    = (float*)d_out;

  // ---- CSC build (shared by both layers) ----
  hipMemsetAsync(bcnt, 0, NBINS * 4, stream);
  bin_hist<<<(EE + HCH - 1) / HCH, 256, 0, stream>>>(col, bcnt, EE);
  bin_scan<<<1, 512, 0, stream>>>(bcnt, bstart, bcur);
  pass1_bin<<<(EE + CH - 1) / CH, 256, 0, stream>>>(row, col, bcur, temp, EE);
  pass2_scatter<<<NBINS, 256, 0, stream>>>(temp, bstart, cursor, deg, dinv, csr, NN);

  // ---- layer 1 ----
  glob1_kernel<<<1, 64, 0, stream>>>(glob_init, w_gn1, b_gn1, g1);
  gemm1<<<(NN + 63) / 64, 256, 0, stream>>>(x, w_nn1, b_nn1, g1, dinv, A, NN);
  gather_agg<0><<<(NN + 3) / 4, 256, 0, stream>>>(csr, cursor, deg, dinv, A, (void*)B, NN);

  // readout -> per-graph globals for layer 2
  hipMemsetAsync(parts, 0, NG * 64 * 4, stream);
  seg_max<<<(NN + 63) / 64, 64, 0, stream>>>((const ushort*)B, gidx, parts, NN, 64);
  glob2_kernel<<<NG, 64, 0, stream>>>(glob_init, parts, w_gg1, b_gg1, w_ng1, b_ng1,
                                      w_gn2, b_gn2, globs2);

  // ---- layer 2 (glob output discarded by reference) ----
  gemm2<<<(NN + 63) / 64, 256, 0, stream>>>(B, w_nn2, b_nn2, globs2, gidx, dinv, A, NN);
  gather_agg<1><<<(NN + 3) / 4, 256, 0, stream>>>(csr, cursor, deg, dinv, A, (void*)out, NN);
}